// Round 12
// baseline (128.695 us; speedup 1.0000x reference)
//
#include <hip/hip_runtime.h>

// DepthDeformConv — round 20: K-split to break the 16-wave/CU ceiling.
//   All r8-r19 kernels share one invariant: full-K-per-wave at 16px/wave
//   -> 4096 waves = 16 waves/CU (4/SIMD) hard ceiling; every in-envelope
//   probe (source/barriers/fences/order/I$/VALU) nulls at main~43us with
//   pipe floors ~11us. This round doubles TLP: taps split 0-4 / 5-8 across
//   wave pairs -> 8192 waves = 32/CU = 8/SIMD. Enablers: no LDS window
//   (corners gather from L2 nhwc, r8-style; the doubled TLP is what hides
//   the ~200cy L2 latency), LDS = sten 6.9KB + padded merge 17KB = 24KB ->
//   4x512thr blocks/CU (2048-thread cap), launch_bounds(512,8) caps VGPR
//   at 64 (compiler naturally ~52, r16). kh=1 waves write partial acc to
//   LDS, one barrier, kh=0 adds + bias + stores (fp32 regroup = ulp-only).
//   No tap barriers, no fences, no setprio (all proven null/negative).

typedef __attribute__((ext_vector_type(8))) short bf16x8;
typedef __attribute__((ext_vector_type(4))) float f32x4;
typedef __attribute__((ext_vector_type(2))) float f32x2;
typedef __attribute__((ext_vector_type(4))) unsigned int u32x4;

#define HH 128
#define WW 128
#define CC 64
#define OO 64
#define HW (128 * 128)

__device__ __forceinline__ unsigned f32_to_bf16_rne(float f) {
    unsigned u = __float_as_uint(f);
    return (u + 0x7FFFu + ((u >> 16) & 1u)) >> 16;
}

__device__ __forceinline__ unsigned cvtpk_bf16(float lo, float hi) {
    unsigned r;
    asm("v_cvt_pk_bf16_f32 %0, %1, %2" : "=v"(r) : "v"(lo), "v"(hi));
    return r;
}

// ---------------- kernel 1: fused NCHW->NHWC bf16 + weight repack ----------------
__global__ __launch_bounds__(256)
void prep_fused20(const float* __restrict__ input,
                  unsigned short* __restrict__ nhwc,
                  const float* __restrict__ weight,
                  unsigned short* __restrict__ wT2)
{
    __shared__ unsigned tile[64][33];
    const int tid = threadIdx.x;
    const int blk = blockIdx.x;

    if (blk >= 2048) {
        const int d  = (blk - 2048) * 256 + tid;    // 0..4607
        const int o  = d & 63;
        const int k8 = d >> 6;                      // 0..71
        const int kt = k8 >> 3;
        const int c8 = k8 & 7;
        u32x4 pk;
        #pragma unroll
        for (int jj = 0; jj < 4; ++jj) {
            unsigned lo = f32_to_bf16_rne(weight[o * 576 + (c8 * 8 + 2 * jj)     * 9 + kt]);
            unsigned hi = f32_to_bf16_rne(weight[o * 576 + (c8 * 8 + 2 * jj + 1) * 9 + kt]);
            pk[jj] = lo | (hi << 16);
        }
        *(u32x4*)(wT2 + (size_t)d * 8) = pk;
        return;
    }

    const int b  = blk >> 9;
    const int y  = (blk >> 2) & 127;
    const int xbase = (blk & 3) * 32;
    #pragma unroll
    for (int it = 0; it < 2; ++it) {
        int flat = it * 256 + tid;          // 0..511
        int c = flat >> 3, x4 = flat & 7;   // 64c x 8 float4-groups
        const f32x4 v = *(const f32x4*)(input + ((b * 64 + c) * 128 + y) * 128 + xbase + x4 * 4);
        tile[c][x4 * 4 + 0] = f32_to_bf16_rne(v[0]);
        tile[c][x4 * 4 + 1] = f32_to_bf16_rne(v[1]);
        tile[c][x4 * 4 + 2] = f32_to_bf16_rne(v[2]);
        tile[c][x4 * 4 + 3] = f32_to_bf16_rne(v[3]);
    }
    __syncthreads();
    {
        int x = tid >> 3, cg = tid & 7;     // 32x * 8 channel-groups
        unsigned r0 = tile[cg * 8 + 0][x], r1 = tile[cg * 8 + 1][x];
        unsigned r2 = tile[cg * 8 + 2][x], r3 = tile[cg * 8 + 3][x];
        unsigned r4 = tile[cg * 8 + 4][x], r5 = tile[cg * 8 + 5][x];
        unsigned r6 = tile[cg * 8 + 6][x], r7 = tile[cg * 8 + 7][x];
        u32x4 pk;
        pk[0] = r0 | (r1 << 16); pk[1] = r2 | (r3 << 16);
        pk[2] = r4 | (r5 << 16); pk[3] = r6 | (r7 << 16);
        *(u32x4*)(nhwc + ((size_t)((b * 128 + y) * 128 + xbase + x)) * 64 + cg * 8) = pk;
    }
}

// ---------------- kernel 2: K-split sample + MFMA, 8 waves/SIMD ----------------
__global__ __launch_bounds__(512, 8)
void ddc_split20(const unsigned short* __restrict__ nhwc,
                 const unsigned short* __restrict__ wT2,
                 const float* __restrict__ offset,
                 const float* __restrict__ mask,
                 const float* __restrict__ bias,
                 float* __restrict__ out)
{
    __shared__ float sten[1728];           // 6.9 KB: 27 planes x 64 px (half row)
    __shared__ float mrg[4352];            // 17 KB: (pxg*64+o)*17 + l15 (padded)

    const int blk0 = blockIdx.x;           // 1024 = 4b * 128h * 2 half-rows
    const int blk  = (blk0 & 7) * 128 + (blk0 >> 3);  // XCD-chunked swizzle
    const int b    = blk >> 8;
    const int h    = (blk >> 1) & 127;
    const int wh   = blk & 1;
    const int tid  = threadIdx.x;
    const int wave = tid >> 6;             // 8 waves: pxg = wave&3, kh = wave>>2
    const int lane = tid & 63;
    const int l15  = lane & 15;
    const int kq   = lane >> 4;
    const int pxg  = wave & 3;
    const int kh   = wave >> 2;            // 0: taps 0-4, 1: taps 5-8
    const int pxl  = pxg * 16 + l15;       // 0..63 within half row
    const int wpix = wh * 64 + pxl;

    f32x4 acc[4];
    #pragma unroll
    for (int mt = 0; mt < 4; ++mt) acc[mt] = (f32x4){0.f, 0.f, 0.f, 0.f};

    const unsigned short* nb = nhwc + (size_t)b * HW * CC;
    const u32x4* wsrc = (const u32x4*)wT2;

    // ---- stage offset/mask planes for this half row (27 x 64 floats) ----
    #pragma unroll
    for (int it = 0; it < 4; ++it) {
        const int f = it * 512 + tid;                 // 0..2047
        if (f < 1728) {
            const int plane = f >> 6;                 // 0..26
            const int x     = f & 63;
            sten[f] = (plane < 18)
                ? offset[((b * 18 + plane)       * 128 + h) * 128 + wh * 64 + x]
                : mask  [((b * 9 + (plane - 18)) * 128 + h) * 128 + wh * 64 + x];
        }
    }
    __syncthreads();

    // ---- tap loop: kh=0 -> kt 0..4, kh=1 -> kt 5..8 (no barriers) ----
    const int kt0 = kh ? 5 : 0;
    const int nkt = kh ? 4 : 5;
    #pragma unroll
    for (int i = 0; i < 5; ++i) {
        if (i < nkt) {
            const int kt = kt0 + i;
            const int ky = (kt * 11) >> 5;            // kt/3 for 0..8
            const int kx = kt - ky * 3;

            const float oy = sten[(2 * kt)     * 64 + pxl];
            const float ox = sten[(2 * kt + 1) * 64 + pxl];
            const float m  = sten[(18 + kt)    * 64 + pxl];

            const float py = (float)(h - 1 + ky) + oy;
            const float px = (float)(wpix - 1 + kx) + ox;
            const float y0f = floorf(py), x0f = floorf(px);
            const int y0 = (int)y0f, x0 = (int)x0f;
            const float wy = py - y0f, wx = px - x0f;
            const int y1 = y0 + 1, x1 = x0 + 1;
            const bool vy0 = (y0 >= 0) & (y0 < HH);
            const bool vy1 = (y1 >= 0) & (y1 < HH);
            const bool vx0 = (x0 >= 0) & (x0 < WW);
            const bool vx1 = (x1 >= 0) & (x1 < WW);
            const int y0c = min(max(y0, 0), HH - 1), y1c = min(max(y1, 0), HH - 1);
            const int x0c = min(max(x0, 0), WW - 1), x1c = min(max(x1, 0), WW - 1);
            const float wy1 = 1.f - wy, wx1 = 1.f - wx;
            const float c00 = (vy0 && vx0) ? wy1 * wx1 * m : 0.f;
            const float c01 = (vy0 && vx1) ? wy1 * wx  * m : 0.f;
            const float c10 = (vy1 && vx0) ? wy  * wx1 * m : 0.f;
            const float c11 = (vy1 && vx1) ? wy  * wx  * m : 0.f;

            const f32x2 vc00 = (f32x2){c00, c00}, vc01 = (f32x2){c01, c01};
            const f32x2 vc10 = (f32x2){c10, c10}, vc11 = (f32x2){c11, c11};

            const unsigned short* p00 = nb + ((size_t)y0c * WW + x0c) * CC;
            const unsigned short* p01 = nb + ((size_t)y0c * WW + x1c) * CC;
            const unsigned short* p10 = nb + ((size_t)y1c * WW + x0c) * CC;
            const unsigned short* p11 = nb + ((size_t)y1c * WW + x1c) * CC;

            #pragma unroll
            for (int ks = 0; ks < 2; ++ks) {
                const int co = (ks * 4 + kq) * 8;     // channel byte offset /2

                const u32x4 w00 = *(const u32x4*)(p00 + co);
                const u32x4 w01 = *(const u32x4*)(p01 + co);
                const u32x4 w10 = *(const u32x4*)(p10 + co);
                const u32x4 w11 = *(const u32x4*)(p11 + co);

                u32x4 pk;
                #pragma unroll
                for (int j = 0; j < 4; ++j) {
                    const f32x2 A = (f32x2){__uint_as_float(w00[j] << 16),
                                            __uint_as_float(w00[j] & 0xFFFF0000u)};
                    const f32x2 B = (f32x2){__uint_as_float(w01[j] << 16),
                                            __uint_as_float(w01[j] & 0xFFFF0000u)};
                    const f32x2 D = (f32x2){__uint_as_float(w10[j] << 16),
                                            __uint_as_float(w10[j] & 0xFFFF0000u)};
                    const f32x2 E = (f32x2){__uint_as_float(w11[j] << 16),
                                            __uint_as_float(w11[j] & 0xFFFF0000u)};
                    const f32x2 S = vc00 * A + vc01 * B + vc10 * D + vc11 * E;
                    pk[j] = cvtpk_bf16(S[0], S[1]);
                }
                const bf16x8 bfrag = __builtin_bit_cast(bf16x8, pk);

                const u32x4* wp = wsrc + (kt * 8 + ks * 4 + kq) * 64 + l15;
                acc[0] = __builtin_amdgcn_mfma_f32_16x16x32_bf16(
                    __builtin_bit_cast(bf16x8, wp[0]),  bfrag, acc[0], 0, 0, 0);
                acc[1] = __builtin_amdgcn_mfma_f32_16x16x32_bf16(
                    __builtin_bit_cast(bf16x8, wp[16]), bfrag, acc[1], 0, 0, 0);
                acc[2] = __builtin_amdgcn_mfma_f32_16x16x32_bf16(
                    __builtin_bit_cast(bf16x8, wp[32]), bfrag, acc[2], 0, 0, 0);
                acc[3] = __builtin_amdgcn_mfma_f32_16x16x32_bf16(
                    __builtin_bit_cast(bf16x8, wp[48]), bfrag, acc[3], 0, 0, 0);
            }
        }
    }

    // ---- merge: kh=1 writes partials, barrier, kh=0 adds + bias + stores ----
    if (kh) {
        #pragma unroll
        for (int mt = 0; mt < 4; ++mt) {
            #pragma unroll
            for (int r = 0; r < 4; ++r) {
                const int o = mt * 16 + kq * 4 + r;
                mrg[(pxg * 64 + o) * 17 + l15] = acc[mt][r];
            }
        }
    }
    __syncthreads();
    if (!kh) {
        #pragma unroll
        for (int mt = 0; mt < 4; ++mt) {
            const f32x4 bv = *(const f32x4*)(bias + mt * 16 + kq * 4);
            #pragma unroll
            for (int r = 0; r < 4; ++r) {
                const int o = mt * 16 + kq * 4 + r;
                out[((b * 64 + o) * 128 + h) * 128 + wpix] =
                    acc[mt][r] + mrg[(pxg * 64 + o) * 17 + l15] + bv[r];
            }
        }
    }
}

extern "C" void kernel_launch(void* const* d_in, const int* in_sizes, int n_in,
                              void* d_out, int out_size, void* d_ws, size_t ws_size,
                              hipStream_t stream)
{
    const float* input  = (const float*)d_in[0];
    // d_in[1] = depth, unused by the reference
    const float* offset = (const float*)d_in[2];
    const float* mask   = (const float*)d_in[3];
    const float* weight = (const float*)d_in[4];
    const float* bias   = (const float*)d_in[5];
    float* out = (float*)d_out;

    unsigned short* nhwc = (unsigned short*)d_ws;                    // 8.39 MB
    unsigned short* wT2  = nhwc + (size_t)4 * HW * CC;               // 73728 B

    prep_fused20<<<dim3(2066), dim3(256), 0, stream>>>(input, nhwc, weight, wT2);
    ddc_split20<<<dim3(1024), dim3(512), 0, stream>>>(nhwc, wT2, offset, mask, bias, out);
}

// Round 13
// 124.012 us; speedup vs baseline: 1.0378x; 1.0378x over previous
//
#include <hip/hip_runtime.h>

// DepthDeformConv — round 21: K-split at 24 waves/CU, spill-free.
//   r20 post-mortem: launch_bounds(512,8) forced VGPR=32 -> scratch spills
//   (WRITE 38MB vs 17MB expected) -> the 71%-occupancy point was
//   confounded. This round is r20 byte-identical except launch_bounds
//   (512,6): VGPR cap 84 (compiler wants ~52-64, r16 -> no spill),
//   3 blocks/CU = 24 waves/CU = 1.5x the r15 envelope. Clean two-point
//   discriminator on the last live axis:
//     latency-bound  -> ddc ~31-36us, dur ~93-99
//     request-rate-bound (r3/r7's original finding) -> ddc ~46-50us,
//       dur ~105-110, theory set exhausted -> declare plateau.
//   Spill check: WRITE_SIZE ~17MB. Merge/numerics identical (passed r20).

typedef __attribute__((ext_vector_type(8))) short bf16x8;
typedef __attribute__((ext_vector_type(4))) float f32x4;
typedef __attribute__((ext_vector_type(2))) float f32x2;
typedef __attribute__((ext_vector_type(4))) unsigned int u32x4;

#define HH 128
#define WW 128
#define CC 64
#define OO 64
#define HW (128 * 128)

__device__ __forceinline__ unsigned f32_to_bf16_rne(float f) {
    unsigned u = __float_as_uint(f);
    return (u + 0x7FFFu + ((u >> 16) & 1u)) >> 16;
}

__device__ __forceinline__ unsigned cvtpk_bf16(float lo, float hi) {
    unsigned r;
    asm("v_cvt_pk_bf16_f32 %0, %1, %2" : "=v"(r) : "v"(lo), "v"(hi));
    return r;
}

// ---------------- kernel 1: fused NCHW->NHWC bf16 + weight repack ----------------
__global__ __launch_bounds__(256)
void prep_fused21(const float* __restrict__ input,
                  unsigned short* __restrict__ nhwc,
                  const float* __restrict__ weight,
                  unsigned short* __restrict__ wT2)
{
    __shared__ unsigned tile[64][33];
    const int tid = threadIdx.x;
    const int blk = blockIdx.x;

    if (blk >= 2048) {
        const int d  = (blk - 2048) * 256 + tid;    // 0..4607
        const int o  = d & 63;
        const int k8 = d >> 6;                      // 0..71
        const int kt = k8 >> 3;
        const int c8 = k8 & 7;
        u32x4 pk;
        #pragma unroll
        for (int jj = 0; jj < 4; ++jj) {
            unsigned lo = f32_to_bf16_rne(weight[o * 576 + (c8 * 8 + 2 * jj)     * 9 + kt]);
            unsigned hi = f32_to_bf16_rne(weight[o * 576 + (c8 * 8 + 2 * jj + 1) * 9 + kt]);
            pk[jj] = lo | (hi << 16);
        }
        *(u32x4*)(wT2 + (size_t)d * 8) = pk;
        return;
    }

    const int b  = blk >> 9;
    const int y  = (blk >> 2) & 127;
    const int xbase = (blk & 3) * 32;
    #pragma unroll
    for (int it = 0; it < 2; ++it) {
        int flat = it * 256 + tid;          // 0..511
        int c = flat >> 3, x4 = flat & 7;   // 64c x 8 float4-groups
        const f32x4 v = *(const f32x4*)(input + ((b * 64 + c) * 128 + y) * 128 + xbase + x4 * 4);
        tile[c][x4 * 4 + 0] = f32_to_bf16_rne(v[0]);
        tile[c][x4 * 4 + 1] = f32_to_bf16_rne(v[1]);
        tile[c][x4 * 4 + 2] = f32_to_bf16_rne(v[2]);
        tile[c][x4 * 4 + 3] = f32_to_bf16_rne(v[3]);
    }
    __syncthreads();
    {
        int x = tid >> 3, cg = tid & 7;     // 32x * 8 channel-groups
        unsigned r0 = tile[cg * 8 + 0][x], r1 = tile[cg * 8 + 1][x];
        unsigned r2 = tile[cg * 8 + 2][x], r3 = tile[cg * 8 + 3][x];
        unsigned r4 = tile[cg * 8 + 4][x], r5 = tile[cg * 8 + 5][x];
        unsigned r6 = tile[cg * 8 + 6][x], r7 = tile[cg * 8 + 7][x];
        u32x4 pk;
        pk[0] = r0 | (r1 << 16); pk[1] = r2 | (r3 << 16);
        pk[2] = r4 | (r5 << 16); pk[3] = r6 | (r7 << 16);
        *(u32x4*)(nhwc + ((size_t)((b * 128 + y) * 128 + xbase + x)) * 64 + cg * 8) = pk;
    }
}

// ---------------- kernel 2: K-split sample + MFMA, 24 waves/CU ----------------
__global__ __launch_bounds__(512, 6)
void ddc_split21(const unsigned short* __restrict__ nhwc,
                 const unsigned short* __restrict__ wT2,
                 const float* __restrict__ offset,
                 const float* __restrict__ mask,
                 const float* __restrict__ bias,
                 float* __restrict__ out)
{
    __shared__ float sten[1728];           // 6.9 KB: 27 planes x 64 px (half row)
    __shared__ float mrg[4352];            // 17 KB: (pxg*64+o)*17 + l15 (padded)

    const int blk0 = blockIdx.x;           // 1024 = 4b * 128h * 2 half-rows
    const int blk  = (blk0 & 7) * 128 + (blk0 >> 3);  // XCD-chunked swizzle
    const int b    = blk >> 8;
    const int h    = (blk >> 1) & 127;
    const int wh   = blk & 1;
    const int tid  = threadIdx.x;
    const int wave = tid >> 6;             // 8 waves: pxg = wave&3, kh = wave>>2
    const int lane = tid & 63;
    const int l15  = lane & 15;
    const int kq   = lane >> 4;
    const int pxg  = wave & 3;
    const int kh   = wave >> 2;            // 0: taps 0-4, 1: taps 5-8
    const int pxl  = pxg * 16 + l15;       // 0..63 within half row
    const int wpix = wh * 64 + pxl;

    f32x4 acc[4];
    #pragma unroll
    for (int mt = 0; mt < 4; ++mt) acc[mt] = (f32x4){0.f, 0.f, 0.f, 0.f};

    const unsigned short* nb = nhwc + (size_t)b * HW * CC;
    const u32x4* wsrc = (const u32x4*)wT2;

    // ---- stage offset/mask planes for this half row (27 x 64 floats) ----
    #pragma unroll
    for (int it = 0; it < 4; ++it) {
        const int f = it * 512 + tid;                 // 0..2047
        if (f < 1728) {
            const int plane = f >> 6;                 // 0..26
            const int x     = f & 63;
            sten[f] = (plane < 18)
                ? offset[((b * 18 + plane)       * 128 + h) * 128 + wh * 64 + x]
                : mask  [((b * 9 + (plane - 18)) * 128 + h) * 128 + wh * 64 + x];
        }
    }
    __syncthreads();

    // ---- tap loop: kh=0 -> kt 0..4, kh=1 -> kt 5..8 (no barriers) ----
    const int kt0 = kh ? 5 : 0;
    const int nkt = kh ? 4 : 5;
    #pragma unroll
    for (int i = 0; i < 5; ++i) {
        if (i < nkt) {
            const int kt = kt0 + i;
            const int ky = (kt * 11) >> 5;            // kt/3 for 0..8
            const int kx = kt - ky * 3;

            const float oy = sten[(2 * kt)     * 64 + pxl];
            const float ox = sten[(2 * kt + 1) * 64 + pxl];
            const float m  = sten[(18 + kt)    * 64 + pxl];

            const float py = (float)(h - 1 + ky) + oy;
            const float px = (float)(wpix - 1 + kx) + ox;
            const float y0f = floorf(py), x0f = floorf(px);
            const int y0 = (int)y0f, x0 = (int)x0f;
            const float wy = py - y0f, wx = px - x0f;
            const int y1 = y0 + 1, x1 = x0 + 1;
            const bool vy0 = (y0 >= 0) & (y0 < HH);
            const bool vy1 = (y1 >= 0) & (y1 < HH);
            const bool vx0 = (x0 >= 0) & (x0 < WW);
            const bool vx1 = (x1 >= 0) & (x1 < WW);
            const int y0c = min(max(y0, 0), HH - 1), y1c = min(max(y1, 0), HH - 1);
            const int x0c = min(max(x0, 0), WW - 1), x1c = min(max(x1, 0), WW - 1);
            const float wy1 = 1.f - wy, wx1 = 1.f - wx;
            const float c00 = (vy0 && vx0) ? wy1 * wx1 * m : 0.f;
            const float c01 = (vy0 && vx1) ? wy1 * wx  * m : 0.f;
            const float c10 = (vy1 && vx0) ? wy  * wx1 * m : 0.f;
            const float c11 = (vy1 && vx1) ? wy  * wx  * m : 0.f;

            const f32x2 vc00 = (f32x2){c00, c00}, vc01 = (f32x2){c01, c01};
            const f32x2 vc10 = (f32x2){c10, c10}, vc11 = (f32x2){c11, c11};

            const unsigned short* p00 = nb + ((size_t)y0c * WW + x0c) * CC;
            const unsigned short* p01 = nb + ((size_t)y0c * WW + x1c) * CC;
            const unsigned short* p10 = nb + ((size_t)y1c * WW + x0c) * CC;
            const unsigned short* p11 = nb + ((size_t)y1c * WW + x1c) * CC;

            #pragma unroll
            for (int ks = 0; ks < 2; ++ks) {
                const int co = (ks * 4 + kq) * 8;     // channel offset (shorts)

                const u32x4 w00 = *(const u32x4*)(p00 + co);
                const u32x4 w01 = *(const u32x4*)(p01 + co);
                const u32x4 w10 = *(const u32x4*)(p10 + co);
                const u32x4 w11 = *(const u32x4*)(p11 + co);

                u32x4 pk;
                #pragma unroll
                for (int j = 0; j < 4; ++j) {
                    const f32x2 A = (f32x2){__uint_as_float(w00[j] << 16),
                                            __uint_as_float(w00[j] & 0xFFFF0000u)};
                    const f32x2 B = (f32x2){__uint_as_float(w01[j] << 16),
                                            __uint_as_float(w01[j] & 0xFFFF0000u)};
                    const f32x2 D = (f32x2){__uint_as_float(w10[j] << 16),
                                            __uint_as_float(w10[j] & 0xFFFF0000u)};
                    const f32x2 E = (f32x2){__uint_as_float(w11[j] << 16),
                                            __uint_as_float(w11[j] & 0xFFFF0000u)};
                    const f32x2 S = vc00 * A + vc01 * B + vc10 * D + vc11 * E;
                    pk[j] = cvtpk_bf16(S[0], S[1]);
                }
                const bf16x8 bfrag = __builtin_bit_cast(bf16x8, pk);

                const u32x4* wp = wsrc + (kt * 8 + ks * 4 + kq) * 64 + l15;
                acc[0] = __builtin_amdgcn_mfma_f32_16x16x32_bf16(
                    __builtin_bit_cast(bf16x8, wp[0]),  bfrag, acc[0], 0, 0, 0);
                acc[1] = __builtin_amdgcn_mfma_f32_16x16x32_bf16(
                    __builtin_bit_cast(bf16x8, wp[16]), bfrag, acc[1], 0, 0, 0);
                acc[2] = __builtin_amdgcn_mfma_f32_16x16x32_bf16(
                    __builtin_bit_cast(bf16x8, wp[32]), bfrag, acc[2], 0, 0, 0);
                acc[3] = __builtin_amdgcn_mfma_f32_16x16x32_bf16(
                    __builtin_bit_cast(bf16x8, wp[48]), bfrag, acc[3], 0, 0, 0);
            }
        }
    }

    // ---- merge: kh=1 writes partials, barrier, kh=0 adds + bias + stores ----
    if (kh) {
        #pragma unroll
        for (int mt = 0; mt < 4; ++mt) {
            #pragma unroll
            for (int r = 0; r < 4; ++r) {
                const int o = mt * 16 + kq * 4 + r;
                mrg[(pxg * 64 + o) * 17 + l15] = acc[mt][r];
            }
        }
    }
    __syncthreads();
    if (!kh) {
        #pragma unroll
        for (int mt = 0; mt < 4; ++mt) {
            const f32x4 bv = *(const f32x4*)(bias + mt * 16 + kq * 4);
            #pragma unroll
            for (int r = 0; r < 4; ++r) {
                const int o = mt * 16 + kq * 4 + r;
                out[((b * 64 + o) * 128 + h) * 128 + wpix] =
                    acc[mt][r] + mrg[(pxg * 64 + o) * 17 + l15] + bv[r];
            }
        }
    }
}

extern "C" void kernel_launch(void* const* d_in, const int* in_sizes, int n_in,
                              void* d_out, int out_size, void* d_ws, size_t ws_size,
                              hipStream_t stream)
{
    const float* input  = (const float*)d_in[0];
    // d_in[1] = depth, unused by the reference
    const float* offset = (const float*)d_in[2];
    const float* mask   = (const float*)d_in[3];
    const float* weight = (const float*)d_in[4];
    const float* bias   = (const float*)d_in[5];
    float* out = (float*)d_out;

    unsigned short* nhwc = (unsigned short*)d_ws;                    // 8.39 MB
    unsigned short* wT2  = nhwc + (size_t)4 * HW * CC;               // 73728 B

    prep_fused21<<<dim3(2066), dim3(256), 0, stream>>>(input, nhwc, weight, wT2);
    ddc_split21<<<dim3(1024), dim3(512), 0, stream>>>(nhwc, wT2, offset, mask, bias, out);
}

// Round 14
// 104.759 us; speedup vs baseline: 1.2285x; 1.1838x over previous
//
#include <hip/hip_runtime.h>

// DepthDeformConv — round 22: REVERT to r15 (session best, 104.6us).
//   r21 resolved the last open axis: spill-free 24 waves/CU left the
//   gather kernel at ~50us (vs ~46 at 16 waves) -> divergent-request
//   service rate is the wall (~45cy/request x ~2300 requests/CU), set by
//   the algorithm's request count, invariant to occupancy and to which
//   pipe (LDS/TA) serves it. All 13 structural theories tested; the five
//   post-r15 probes (spin-fusion, inline transpose, issue order, fences,
//   K-split x2) all regressed. Decomposition: fill ~45 (harness) + prep+
//   gaps ~15 + main ~44 (request floor) = 104.6 = r15. This round banks
//   the minimum: r15 byte-identical (1024thr / 16 waves / 8-row 128KB
//   window / 27KB LDS sten / slim per-ks chunks / packed f32x2 blend +
//   v_cvt_pk_bf16_f32 / L2 weights / single barrier / XCD swizzle).

typedef __attribute__((ext_vector_type(8))) short bf16x8;
typedef __attribute__((ext_vector_type(4))) float f32x4;
typedef __attribute__((ext_vector_type(2))) float f32x2;
typedef __attribute__((ext_vector_type(4))) unsigned int u32x4;

#define HH 128
#define WW 128
#define CC 64
#define OO 64
#define HW (128 * 128)

__device__ __forceinline__ unsigned f32_to_bf16_rne(float f) {
    unsigned u = __float_as_uint(f);
    return (u + 0x7FFFu + ((u >> 16) & 1u)) >> 16;
}

// ---------------- kernel 1: fused NCHW->NHWC bf16 + weight repack ----------------
__global__ __launch_bounds__(256)
void prep_fused22(const float* __restrict__ input,
                  unsigned short* __restrict__ nhwc,
                  const float* __restrict__ weight,
                  unsigned short* __restrict__ wT2)
{
    __shared__ unsigned tile[64][33];
    const int tid = threadIdx.x;
    const int blk = blockIdx.x;

    if (blk >= 2048) {
        // weight repack: wT2[(kt*8 + c8)*64 + o] = bf16 w for ch c8*8..+7, tap kt
        const int d  = (blk - 2048) * 256 + tid;    // 0..4607
        const int o  = d & 63;
        const int k8 = d >> 6;                      // 0..71
        const int kt = k8 >> 3;
        const int c8 = k8 & 7;
        u32x4 pk;
        #pragma unroll
        for (int jj = 0; jj < 4; ++jj) {
            unsigned lo = f32_to_bf16_rne(weight[o * 576 + (c8 * 8 + 2 * jj)     * 9 + kt]);
            unsigned hi = f32_to_bf16_rne(weight[o * 576 + (c8 * 8 + 2 * jj + 1) * 9 + kt]);
            pk[jj] = lo | (hi << 16);
        }
        *(u32x4*)(wT2 + (size_t)d * 8) = pk;
        return;
    }

    const int b  = blk >> 9;
    const int y  = (blk >> 2) & 127;
    const int xbase = (blk & 3) * 32;
    #pragma unroll
    for (int it = 0; it < 2; ++it) {
        int flat = it * 256 + tid;          // 0..511
        int c = flat >> 3, x4 = flat & 7;   // 64c x 8 float4-groups
        const f32x4 v = *(const f32x4*)(input + ((b * 64 + c) * 128 + y) * 128 + xbase + x4 * 4);
        tile[c][x4 * 4 + 0] = f32_to_bf16_rne(v[0]);
        tile[c][x4 * 4 + 1] = f32_to_bf16_rne(v[1]);
        tile[c][x4 * 4 + 2] = f32_to_bf16_rne(v[2]);
        tile[c][x4 * 4 + 3] = f32_to_bf16_rne(v[3]);
    }
    __syncthreads();
    {
        int x = tid >> 3, cg = tid & 7;     // 32x * 8 channel-groups
        unsigned r0 = tile[cg * 8 + 0][x], r1 = tile[cg * 8 + 1][x];
        unsigned r2 = tile[cg * 8 + 2][x], r3 = tile[cg * 8 + 3][x];
        unsigned r4 = tile[cg * 8 + 4][x], r5 = tile[cg * 8 + 5][x];
        unsigned r6 = tile[cg * 8 + 6][x], r7 = tile[cg * 8 + 7][x];
        u32x4 pk;
        pk[0] = r0 | (r1 << 16); pk[1] = r2 | (r3 << 16);
        pk[2] = r4 | (r5 << 16); pk[3] = r6 | (r7 << 16);
        *(u32x4*)(nhwc + ((size_t)((b * 128 + y) * 128 + xbase + x)) * 64 + cg * 8) = pk;
    }
}

// ---------------- kernel 2: fused sample + MFMA, 16-wave slim body ----------------
__global__ __launch_bounds__(1024)
void ddc_slim22(const unsigned short* __restrict__ nhwc,
                const unsigned short* __restrict__ wT2,
                const float* __restrict__ offset,
                const float* __restrict__ mask,
                const float* __restrict__ bias,
                float* __restrict__ out)
{
    // 8-row bf16 NHWC window, chunk-swizzled: LDS u32x4 index
    //   idx(slot,x,c8pos) = slot*1024 + x*8 + c8pos, holding source chunk
    //   c8pos ^ (x&7). Reader at chunk ch uses pos = ch ^ (x&7).
    __shared__ u32x4 win[8192];            // 128 KB
    __shared__ float sten[6912];           // 27 KB: [plane 0..26][hr 0..1][x 0..127]

    const int blk0 = blockIdx.x;           // 256 = 4b * 64 h-pairs
    const int blk  = (blk0 & 7) * 32 + (blk0 >> 3);   // XCD-chunked swizzle
    const int b    = blk >> 6;
    const int h0   = (blk & 63) * 2;
    const int ys   = h0 - 3;               // window start row
    const int tid  = threadIdx.x;
    const int wave = tid >> 6;             // 16 waves
    const int lane = tid & 63;
    const int l15  = lane & 15;            // pixel within group / o-row (A)
    const int kq   = lane >> 4;            // k-chunk quad (0..3)
    const int hr   = wave >> 3;            // waves 0-7 -> h0, 8-15 -> h0+1
    const int h    = h0 + hr;
    const int wpix = (wave & 7) * 16 + l15;

    f32x4 acc[4];
    #pragma unroll
    for (int mt = 0; mt < 4; ++mt) acc[mt] = (f32x4){0.f, 0.f, 0.f, 0.f};

    const unsigned short* nb = nhwc + (size_t)b * HW * CC;
    const u32x4* wsrc = (const u32x4*)wT2;

    // ---- stage offset/mask planes for both rows (27 planes x 2 x 128) ----
    #pragma unroll
    for (int it = 0; it < 7; ++it) {
        const int f = it * 1024 + tid;                // 0..7167
        if (f < 6912) {
            const int plane = f >> 8;                 // 0..26
            const int fr    = (f >> 7) & 1;
            const int x     = f & 127;
            sten[f] = (plane < 18)
                ? offset[((b * 18 + plane)      * 128 + (h0 + fr)) * 128 + x]
                : mask  [((b * 9 + (plane - 18))* 128 + (h0 + fr)) * 128 + x];
        }
    }

    // ---- stage window rows ys..ys+7 (swizzled source, linear LDS dest) ----
    #pragma unroll
    for (int slot = 0; slot < 8; ++slot) {
        const int y = ys + slot;
        if (y >= 0 && y < HH) {
            const int q  = tid;                       // 0..1023 = one full row
            const int x  = q >> 3;
            const int c8 = q & 7;
            win[slot * 1024 + q] =
                *(const u32x4*)(nb + ((size_t)(y * WW + x)) * CC + ((c8 ^ (x & 7)) << 3));
        }
    }
    __syncthreads();                                  // the ONLY barrier

    // ---- K loop: fully unrolled, barrier-free, slim per-ks chunks ----
    #pragma unroll
    for (int kt = 0; kt < 9; ++kt) {
        // stencil scalars from LDS (16-lane broadcast, conflict-free)
        const float oy = sten[(2 * kt)     * 256 + hr * 128 + wpix];
        const float ox = sten[(2 * kt + 1) * 256 + hr * 128 + wpix];
        const float m  = sten[(18 + kt)    * 256 + hr * 128 + wpix];

        const float py = (float)(h - 1 + kt / 3) + oy;
        const float px = (float)(wpix - 1 + kt % 3) + ox;
        const float y0f = floorf(py), x0f = floorf(px);
        const int y0 = (int)y0f, x0 = (int)x0f;
        const float wy = py - y0f, wx = px - x0f;
        const int y1 = y0 + 1, x1 = x0 + 1;
        const bool vy0 = (y0 >= 0) & (y0 < HH);
        const bool vy1 = (y1 >= 0) & (y1 < HH);
        const bool vx0 = (x0 >= 0) & (x0 < WW);
        const bool vx1 = (x1 >= 0) & (x1 < WW);
        const int y0c = min(max(y0, 0), HH - 1), y1c = min(max(y1, 0), HH - 1);
        const int x0c = min(max(x0, 0), WW - 1), x1c = min(max(x1, 0), WW - 1);
        const float wy1 = 1.f - wy, wx1 = 1.f - wx;
        const float c00 = (vy0 && vx0) ? wy1 * wx1 * m : 0.f;
        const float c01 = (vy0 && vx1) ? wy1 * wx  * m : 0.f;
        const float c10 = (vy1 && vx0) ? wy  * wx1 * m : 0.f;
        const float c11 = (vy1 && vx1) ? wy  * wx  * m : 0.f;

        const int s0 = y0c - ys, s1 = y1c - ys;
        const bool in0 = ((unsigned)s0 < 8u);
        const bool in1 = ((unsigned)s1 < 8u);
        const int r0 = (in0 ? s0 : 0) * 1024;
        const int r1 = (in1 ? s1 : 0) * 1024;
        const int bx0 = x0c * 8, sx0 = x0c & 7;
        const int bx1 = x1c * 8, sx1 = x1c & 7;

        const f32x2 vc00 = (f32x2){c00, c00}, vc01 = (f32x2){c01, c01};
        const f32x2 vc10 = (f32x2){c10, c10}, vc11 = (f32x2){c11, c11};

        #pragma unroll
        for (int ks = 0; ks < 2; ++ks) {
            const int ch = ks * 4 + kq;       // this lane's 8-channel chunk

            u32x4 w00 = win[r0 + bx0 + (ch ^ sx0)];
            u32x4 w01 = win[r0 + bx1 + (ch ^ sx1)];
            u32x4 w10 = win[r1 + bx0 + (ch ^ sx0)];
            u32x4 w11 = win[r1 + bx1 + (ch ^ sx1)];
            if (!in0) {                       // rare: |oy| past window
                w00 = *(const u32x4*)(nb + ((size_t)y0c * WW + x0c) * CC + ch * 8);
                w01 = *(const u32x4*)(nb + ((size_t)y0c * WW + x1c) * CC + ch * 8);
            }
            if (!in1) {
                w10 = *(const u32x4*)(nb + ((size_t)y1c * WW + x0c) * CC + ch * 8);
                w11 = *(const u32x4*)(nb + ((size_t)y1c * WW + x1c) * CC + ch * 8);
            }

            u32x4 pk;
            #pragma unroll
            for (int j = 0; j < 4; ++j) {
                const f32x2 A = (f32x2){__uint_as_float(w00[j] << 16),
                                        __uint_as_float(w00[j] & 0xFFFF0000u)};
                const f32x2 B = (f32x2){__uint_as_float(w01[j] << 16),
                                        __uint_as_float(w01[j] & 0xFFFF0000u)};
                const f32x2 D = (f32x2){__uint_as_float(w10[j] << 16),
                                        __uint_as_float(w10[j] & 0xFFFF0000u)};
                const f32x2 E = (f32x2){__uint_as_float(w11[j] << 16),
                                        __uint_as_float(w11[j] & 0xFFFF0000u)};
                const f32x2 S = vc00 * A + vc01 * B + vc10 * D + vc11 * E;
                unsigned r;
                asm("v_cvt_pk_bf16_f32 %0, %1, %2" : "=v"(r) : "v"(S[0]), "v"(S[1]));
                pk[j] = r;
            }
            const bf16x8 bfrag = __builtin_bit_cast(bf16x8, pk);

            // A-fragments from global (wT2 72KB, L2-resident)
            const u32x4* wp = wsrc + (kt * 8 + ks * 4 + kq) * 64 + l15;
            acc[0] = __builtin_amdgcn_mfma_f32_16x16x32_bf16(
                __builtin_bit_cast(bf16x8, wp[0]),  bfrag, acc[0], 0, 0, 0);
            acc[1] = __builtin_amdgcn_mfma_f32_16x16x32_bf16(
                __builtin_bit_cast(bf16x8, wp[16]), bfrag, acc[1], 0, 0, 0);
            acc[2] = __builtin_amdgcn_mfma_f32_16x16x32_bf16(
                __builtin_bit_cast(bf16x8, wp[32]), bfrag, acc[2], 0, 0, 0);
            acc[3] = __builtin_amdgcn_mfma_f32_16x16x32_bf16(
                __builtin_bit_cast(bf16x8, wp[48]), bfrag, acc[3], 0, 0, 0);
        }
    }

    // ---- epilogue: C/D layout col=lane&15 (pixel), row=kq*4+reg (o) ----
    #pragma unroll
    for (int mt = 0; mt < 4; ++mt) {
        const f32x4 bv = *(const f32x4*)(bias + mt * 16 + kq * 4);
        #pragma unroll
        for (int r = 0; r < 4; ++r) {
            const int o = mt * 16 + kq * 4 + r;
            out[((b * 64 + o) * 128 + h) * 128 + wpix] = acc[mt][r] + bv[r];
        }
    }
}

extern "C" void kernel_launch(void* const* d_in, const int* in_sizes, int n_in,
                              void* d_out, int out_size, void* d_ws, size_t ws_size,
                              hipStream_t stream)
{
    const float* input  = (const float*)d_in[0];
    // d_in[1] = depth, unused by the reference
    const float* offset = (const float*)d_in[2];
    const float* mask   = (const float*)d_in[3];
    const float* weight = (const float*)d_in[4];
    const float* bias   = (const float*)d_in[5];
    float* out = (float*)d_out;

    unsigned short* nhwc = (unsigned short*)d_ws;                    // 8.39 MB
    unsigned short* wT2  = nhwc + (size_t)4 * HW * CC;               // 73728 B

    prep_fused22<<<dim3(2066), dim3(256), 0, stream>>>(input, nhwc, weight, wT2);
    ddc_slim22<<<dim3(256), dim3(1024), 0, stream>>>(nhwc, wT2, offset, mask, bias, out);
}